// Round 1
// baseline (321.185 us; speedup 1.0000x reference)
//
#include <hip/hip_runtime.h>

typedef __attribute__((ext_vector_type(8))) short short8;
typedef __attribute__((ext_vector_type(4))) float f32x4;

__device__ __forceinline__ unsigned short f2bf(float f){
  union { float f; unsigned int u; } cv; cv.f = f;
  unsigned int u = cv.u;
  u = (u + 0x7fffu + ((u >> 16) & 1u)) >> 16;
  return (unsigned short)u;
}

// ---------------- reduction: per-batch mean / rstd ----------------
__global__ __launch_bounds__(256) void reduce_partial_k(const float* __restrict__ x,
                                                        float2* __restrict__ partial){
  const int b = blockIdx.y, blk = blockIdx.x;
  const float4* xp = (const float4*)(x + (size_t)b*1048576 + (size_t)blk*16384);
  float s = 0.f, sq = 0.f;
  #pragma unroll
  for (int i = 0; i < 16; ++i){
    float4 v = xp[threadIdx.x + i*256];
    s  += v.x + v.y + v.z + v.w;
    sq += v.x*v.x + v.y*v.y + v.z*v.z + v.w*v.w;
  }
  #pragma unroll
  for (int m = 1; m < 64; m <<= 1){ s += __shfl_xor(s, m); sq += __shfl_xor(sq, m); }
  __shared__ float2 acc[4];
  if ((threadIdx.x & 63) == 0) acc[threadIdx.x >> 6] = make_float2(s, sq);
  __syncthreads();
  if (threadIdx.x == 0){
    float S = 0.f, Q = 0.f;
    for (int i = 0; i < 4; ++i){ S += acc[i].x; Q += acc[i].y; }
    partial[b*64 + blk] = make_float2(S, Q);
  }
}

__global__ __launch_bounds__(256) void reduce_final_k(const float2* __restrict__ partial,
                                                      float2* __restrict__ stats){
  const int w = threadIdx.x >> 6, lane = threadIdx.x & 63;
  float2 p = partial[w*64 + lane];
  float s = p.x, q = p.y;
  #pragma unroll
  for (int m = 1; m < 64; m <<= 1){ s += __shfl_xor(s, m); q += __shfl_xor(q, m); }
  if (lane == 0){
    const float inv = 1.0f/1048576.0f;
    float mean = s*inv;
    float var  = q*inv - mean*mean;
    stats[w] = make_float2(mean, rsqrtf(var + 1e-6f));
  }
}

// ---------------- weight conversion (fold scale*log2e into Q) ----------------
__global__ __launch_bounds__(256) void convert_w_k(const float* __restrict__ qkv_w,
                                                   const float* __restrict__ qkv_b,
                                                   const float* __restrict__ proj_w,
                                                   unsigned short* __restrict__ Wqk,
                                                   unsigned short* __restrict__ Wv,
                                                   unsigned short* __restrict__ Wp,
                                                   float* __restrict__ bias_qk){
  const float SQ = 0.0625f * 1.44269504088896340736f; // (C^-0.5) * log2(e)
  int id = blockIdx.x * 256 + threadIdx.x;
  if (id < 131072){                       // q,k rows (o < 512)
    int o = id >> 8;
    float sc = (o < 256) ? SQ : 1.0f;
    Wqk[id] = f2bf(qkv_w[id] * sc);
    if (id < 512) bias_qk[id] = qkv_b[id] * ((id < 256) ? SQ : 1.0f);
  } else if (id < 196608){                // v rows (o in [512,768))
    Wv[id - 131072] = f2bf(qkv_w[id]);
  } else {                                // proj
    int j = id - 196608;
    Wp[j] = f2bf(proj_w[j]);
  }
}

// ---------------- GroupNorm + transpose: x[b][c][n] -> xn_t[b][n][c] bf16 ----------------
__global__ __launch_bounds__(256) void norm_transpose_k(const float* __restrict__ x,
                                                        const float* __restrict__ gamma,
                                                        const float* __restrict__ beta,
                                                        const float2* __restrict__ stats,
                                                        unsigned short* __restrict__ xnt){
  __shared__ float tile[64][65];
  const int b = blockIdx.z, n0 = blockIdx.x*64, c0 = blockIdx.y*64;
  const float2 st = stats[b];
  const int t = threadIdx.x;
  const int col = t & 63, rb = t >> 6;
  #pragma unroll
  for (int i = 0; i < 16; ++i){
    int rr = i*4 + rb;
    float xv = x[((size_t)b*256 + c0 + rr)*4096 + n0 + col];
    tile[rr][col] = (xv - st.x) * st.y * gamma[c0+rr] + beta[c0+rr];
  }
  __syncthreads();
  #pragma unroll
  for (int i = 0; i < 16; ++i){
    int nr = i*4 + rb;
    xnt[((size_t)b*4096 + n0 + nr)*256 + c0 + col] = f2bf(tile[col][nr]);
  }
}

// ---------------- NT GEMM: C[m][n] = sum_k A[m][k]*B[n][k], K=256 ----------------
__global__ __launch_bounds__(256) void gemm_nt_k(const unsigned short* __restrict__ A,
                                                 const unsigned short* __restrict__ B,
                                                 int lda, int ldb, long sA, long sB,
                                                 const float* __restrict__ bias_m,
                                                 const float* __restrict__ bias_n,
                                                 const float* __restrict__ resid, long sR,
                                                 float* __restrict__ outF,
                                                 unsigned short* __restrict__ outB,
                                                 int ldc, long sC){
  __shared__ unsigned short As[64][40];
  __shared__ unsigned short Bs[64][40];
  const int b  = blockIdx.z;
  const int m0 = blockIdx.x * 64, n0 = blockIdx.y * 64;
  const unsigned short* Ab = A + (size_t)b * sA;
  const unsigned short* Bb = B + (size_t)b * sB;
  const int t = threadIdx.x;
  const int lane = t & 63, w = t >> 6;
  const int g = lane >> 4, r = lane & 15;
  const int wm = (w >> 1) * 32, wn = (w & 1) * 32;
  const int lrow = t >> 2, lcol = (t & 3) * 8;
  f32x4 acc00 = {0,0,0,0}, acc01 = {0,0,0,0}, acc10 = {0,0,0,0}, acc11 = {0,0,0,0};
  for (int ks = 0; ks < 8; ++ks){
    short8 av = *(const short8*)(Ab + (size_t)(m0 + lrow) * lda + ks*32 + lcol);
    short8 bv = *(const short8*)(Bb + (size_t)(n0 + lrow) * ldb + ks*32 + lcol);
    __syncthreads();
    *(short8*)&As[lrow][lcol] = av;
    *(short8*)&Bs[lrow][lcol] = bv;
    __syncthreads();
    short8 af0 = *(const short8*)&As[wm + r][g*8];
    short8 af1 = *(const short8*)&As[wm + 16 + r][g*8];
    short8 bf0 = *(const short8*)&Bs[wn + r][g*8];
    short8 bf1 = *(const short8*)&Bs[wn + 16 + r][g*8];
    acc00 = __builtin_amdgcn_mfma_f32_16x16x32_bf16(af0, bf0, acc00, 0, 0, 0);
    acc01 = __builtin_amdgcn_mfma_f32_16x16x32_bf16(af0, bf1, acc01, 0, 0, 0);
    acc10 = __builtin_amdgcn_mfma_f32_16x16x32_bf16(af1, bf0, acc10, 0, 0, 0);
    acc11 = __builtin_amdgcn_mfma_f32_16x16x32_bf16(af1, bf1, acc11, 0, 0, 0);
  }
  f32x4 accs[2][2] = {{acc00, acc01},{acc10, acc11}};
  #pragma unroll
  for (int mi = 0; mi < 2; ++mi)
    #pragma unroll
    for (int ni = 0; ni < 2; ++ni)
      #pragma unroll
      for (int j = 0; j < 4; ++j){
        int gm = m0 + wm + mi*16 + g*4 + j;
        int gn = n0 + wn + ni*16 + r;
        float vv = accs[mi][ni][j];
        if (bias_m) vv += bias_m[gm];
        if (bias_n) vv += bias_n[gn];
        if (resid)  vv += resid[(size_t)b*sR + (size_t)gm*ldc + gn];
        size_t off = (size_t)b*sC + (size_t)gm*ldc + gn;
        if (outB) outB[off] = f2bf(vv); else outF[off] = vv;
      }
}

// ---------------- flash attention: q,k in qk[b][n][512] (q=c<256,k=c>=256), v[b][c][n] ----------------
__global__ __launch_bounds__(256) void attn_k(const unsigned short* __restrict__ qk,
                                              const unsigned short* __restrict__ vbuf,
                                              unsigned short* __restrict__ ho){
  __shared__ unsigned short Ks[32][264];   // [k_row][c]
  __shared__ unsigned short Vs[256][40];   // [c][k_row]
  __shared__ unsigned short Ps[64][40];    // [q_row][k_row]
  const int b = blockIdx.y;
  const int q0 = blockIdx.x * 64;
  const int t = threadIdx.x;
  const int w = t >> 6;
  const int lane = t & 63;
  const int g = lane >> 4, r = lane & 15;
  const unsigned short* qkb = qk + (size_t)b * 4096 * 512;
  const unsigned short* vb  = vbuf + (size_t)b * 256 * 4096;

  short8 qf[8];
  {
    const unsigned short* qrowp = qkb + (size_t)(q0 + w*16 + r) * 512;
    #pragma unroll
    for (int kk = 0; kk < 8; ++kk)
      qf[kk] = *(const short8*)(qrowp + kk*32 + g*8);
  }
  f32x4 oacc[16];
  #pragma unroll
  for (int i = 0; i < 16; ++i) oacc[i] = (f32x4){0.f,0.f,0.f,0.f};
  float mrun[4] = {-INFINITY,-INFINITY,-INFINITY,-INFINITY};
  float lrun[4] = {0.f,0.f,0.f,0.f};

  for (int kt = 0; kt < 128; ++kt){
    const int k0 = kt * 32;
    #pragma unroll
    for (int i = 0; i < 4; ++i){
      int cid = t + i*256;
      int row = cid >> 5, c8 = (cid & 31) * 8;
      *(short8*)&Ks[row][c8] = *(const short8*)(qkb + (size_t)(k0+row)*512 + 256 + c8);
    }
    #pragma unroll
    for (int i = 0; i < 4; ++i){
      int cid = t + i*256;
      int row = cid >> 2, c8 = (cid & 3) * 8;
      *(short8*)&Vs[row][c8] = *(const short8*)(vb + (size_t)row*4096 + k0 + c8);
    }
    __syncthreads();

    // S = Q K^T (pre-scaled by C^-0.5 * log2e)
    f32x4 s0 = {0.f,0.f,0.f,0.f}, s1 = {0.f,0.f,0.f,0.f};
    #pragma unroll
    for (int kk = 0; kk < 8; ++kk){
      short8 b0 = *(const short8*)&Ks[r][kk*32 + g*8];
      short8 b1 = *(const short8*)&Ks[16 + r][kk*32 + g*8];
      s0 = __builtin_amdgcn_mfma_f32_16x16x32_bf16(qf[kk], b0, s0, 0, 0, 0);
      s1 = __builtin_amdgcn_mfma_f32_16x16x32_bf16(qf[kk], b1, s1, 0, 0, 0);
    }

    // online softmax (base-2)
    #pragma unroll
    for (int j = 0; j < 4; ++j){
      float mx = fmaxf(s0[j], s1[j]);
      mx = fmaxf(mx, __shfl_xor(mx, 1));
      mx = fmaxf(mx, __shfl_xor(mx, 2));
      mx = fmaxf(mx, __shfl_xor(mx, 4));
      mx = fmaxf(mx, __shfl_xor(mx, 8));
      float mnew  = fmaxf(mrun[j], mx);
      float alpha = exp2f(mrun[j] - mnew);
      float p0 = exp2f(s0[j] - mnew);
      float p1 = exp2f(s1[j] - mnew);
      float rs = p0 + p1;
      rs += __shfl_xor(rs, 1);
      rs += __shfl_xor(rs, 2);
      rs += __shfl_xor(rs, 4);
      rs += __shfl_xor(rs, 8);
      lrun[j] = lrun[j]*alpha + rs;
      mrun[j] = mnew;
      #pragma unroll
      for (int cb = 0; cb < 16; ++cb) oacc[cb][j] *= alpha;
      Ps[w*16 + g*4 + j][r]      = f2bf(p0);
      Ps[w*16 + g*4 + j][16 + r] = f2bf(p1);
    }

    // O += P V   (P rows are wave-private; LDS dep within wave handled by compiler waitcnt)
    short8 pa = *(const short8*)&Ps[w*16 + r][g*8];
    #pragma unroll
    for (int cb = 0; cb < 16; ++cb){
      short8 bv = *(const short8*)&Vs[cb*16 + r][g*8];
      oacc[cb] = __builtin_amdgcn_mfma_f32_16x16x32_bf16(pa, bv, oacc[cb], 0, 0, 0);
    }
    __syncthreads();
  }

  #pragma unroll
  for (int j = 0; j < 4; ++j){
    float inv = 1.0f / lrun[j];
    size_t rowoff = (size_t)(b*4096 + q0 + w*16 + g*4 + j) * 256;
    #pragma unroll
    for (int cb = 0; cb < 16; ++cb)
      ho[rowoff + cb*16 + r] = f2bf(oacc[cb][j] * inv);
  }
}

// ---------------- launch ----------------
extern "C" void kernel_launch(void* const* d_in, const int* in_sizes, int n_in,
                              void* d_out, int out_size, void* d_ws, size_t ws_size,
                              hipStream_t stream){
  const float* x      = (const float*)d_in[0];
  const float* gamma  = (const float*)d_in[1];
  const float* beta   = (const float*)d_in[2];
  const float* qkv_w  = (const float*)d_in[3];
  const float* qkv_b  = (const float*)d_in[4];
  const float* proj_w = (const float*)d_in[5];
  const float* proj_b = (const float*)d_in[6];
  float* out = (float*)d_out;
  char* ws = (char*)d_ws;

  float2* partial        = (float2*)(ws + 0);        // 2048 B
  float2* stats          = (float2*)(ws + 2048);     // 32 B
  float*  bias_qk        = (float*)(ws + 4096);      // 2048 B
  unsigned short* Wqk    = (unsigned short*)(ws + 8192);      // 512x256 bf16
  unsigned short* Wv     = (unsigned short*)(ws + 270336);    // 256x256
  unsigned short* Wp     = (unsigned short*)(ws + 401408);    // 256x256
  unsigned short* xnt    = (unsigned short*)(ws + 532480);    // 4x4096x256 bf16 (8.4 MB)
  unsigned short* qkbuf  = (unsigned short*)(ws + 8921088);   // 4x4096x512 bf16 (16.8 MB)
  unsigned short* vbuf   = (unsigned short*)(ws + 25698304);  // 4x256x4096 bf16 (8.4 MB)
  unsigned short* ho     = xnt;  // xnt dead after QKV gemms -> reuse for attention output

  reduce_partial_k<<<dim3(64,4), 256, 0, stream>>>(x, partial);
  reduce_final_k<<<1, 256, 0, stream>>>(partial, stats);
  convert_w_k<<<1024, 256, 0, stream>>>(qkv_w, qkv_b, proj_w, Wqk, Wv, Wp, bias_qk);
  norm_transpose_k<<<dim3(64,4,4), 256, 0, stream>>>(x, gamma, beta, stats, xnt);
  // qk[b][n][o] = xn_t[b][n][:] . Wqk[o][:]   (M=4096, N=512)
  gemm_nt_k<<<dim3(64,8,4), 256, 0, stream>>>(xnt, Wqk, 256, 256, 4096L*256, 0,
      nullptr, bias_qk, nullptr, 0, nullptr, qkbuf, 512, 4096L*512);
  // v[b][o][n] = Wv[o][:] . xn_t[b][n][:]     (M=256, N=4096)
  gemm_nt_k<<<dim3(4,64,4), 256, 0, stream>>>(Wv, xnt, 256, 256, 0, 4096L*256,
      qkv_b + 512, nullptr, nullptr, 0, nullptr, vbuf, 4096, 256L*4096);
  attn_k<<<dim3(64,4), 256, 0, stream>>>(qkbuf, vbuf, ho);
  // out[b][o][n] = Wp[o][:] . ho[b][n][:] + proj_b[o] + x[b][o][n]
  gemm_nt_k<<<dim3(4,64,4), 256, 0, stream>>>(Wp, ho, 256, 256, 0, 4096L*256,
      proj_b, nullptr, x, 1048576L, out, nullptr, 4096, 1048576L);
}

// Round 2
// 230.546 us; speedup vs baseline: 1.3932x; 1.3932x over previous
//
#include <hip/hip_runtime.h>

typedef __attribute__((ext_vector_type(8))) short short8;
typedef __attribute__((ext_vector_type(4))) float f32x4;

__device__ __forceinline__ unsigned short f2bf(float f){
  union { float f; unsigned int u; } cv; cv.f = f;
  unsigned int u = cv.u;
  u = (u + 0x7fffu + ((u >> 16) & 1u)) >> 16;
  return (unsigned short)u;
}

typedef unsigned int u32g __attribute__((address_space(1)));
typedef unsigned int u32l __attribute__((address_space(3)));
__device__ __forceinline__ void gload16(const void* g, void* l){
  __builtin_amdgcn_global_load_lds((const u32g*)g, (u32l*)l, 16, 0, 0);
}

// ---------------- reduction: per-batch mean / rstd ----------------
__global__ __launch_bounds__(256) void reduce_partial_k(const float* __restrict__ x,
                                                        float2* __restrict__ partial){
  const int b = blockIdx.y, blk = blockIdx.x;
  const float4* xp = (const float4*)(x + (size_t)b*1048576 + (size_t)blk*16384);
  float s = 0.f, sq = 0.f;
  #pragma unroll
  for (int i = 0; i < 16; ++i){
    float4 v = xp[threadIdx.x + i*256];
    s  += v.x + v.y + v.z + v.w;
    sq += v.x*v.x + v.y*v.y + v.z*v.z + v.w*v.w;
  }
  #pragma unroll
  for (int m = 1; m < 64; m <<= 1){ s += __shfl_xor(s, m); sq += __shfl_xor(sq, m); }
  __shared__ float2 acc[4];
  if ((threadIdx.x & 63) == 0) acc[threadIdx.x >> 6] = make_float2(s, sq);
  __syncthreads();
  if (threadIdx.x == 0){
    float S = 0.f, Q = 0.f;
    for (int i = 0; i < 4; ++i){ S += acc[i].x; Q += acc[i].y; }
    partial[b*64 + blk] = make_float2(S, Q);
  }
}

__global__ __launch_bounds__(256) void reduce_final_k(const float2* __restrict__ partial,
                                                      float2* __restrict__ stats){
  const int w = threadIdx.x >> 6, lane = threadIdx.x & 63;
  float2 p = partial[w*64 + lane];
  float s = p.x, q = p.y;
  #pragma unroll
  for (int m = 1; m < 64; m <<= 1){ s += __shfl_xor(s, m); q += __shfl_xor(q, m); }
  if (lane == 0){
    const float inv = 1.0f/1048576.0f;
    float mean = s*inv;
    float var  = q*inv - mean*mean;
    stats[w] = make_float2(mean, rsqrtf(var + 1e-6f));
  }
}

// ---------------- weight conversion (fold scale*log2e into Q) ----------------
__global__ __launch_bounds__(256) void convert_w_k(const float* __restrict__ qkv_w,
                                                   const float* __restrict__ qkv_b,
                                                   const float* __restrict__ proj_w,
                                                   unsigned short* __restrict__ Wqk,
                                                   unsigned short* __restrict__ Wv,
                                                   unsigned short* __restrict__ Wp,
                                                   float* __restrict__ bias_qk){
  const float SQ = 0.0625f * 1.44269504088896340736f; // (C^-0.5) * log2(e)
  int id = blockIdx.x * 256 + threadIdx.x;
  if (id < 131072){                       // q,k rows (o < 512)
    int o = id >> 8;
    float sc = (o < 256) ? SQ : 1.0f;
    Wqk[id] = f2bf(qkv_w[id] * sc);
    if (id < 512) bias_qk[id] = qkv_b[id] * ((id < 256) ? SQ : 1.0f);
  } else if (id < 196608){                // v rows (o in [512,768))
    Wv[id - 131072] = f2bf(qkv_w[id]);
  } else {                                // proj
    int j = id - 196608;
    Wp[j] = f2bf(proj_w[j]);
  }
}

// ---------------- GroupNorm + transpose: x[b][c][n] -> xn_t[b][n][c] bf16 ----------------
__global__ __launch_bounds__(256) void norm_transpose_k(const float* __restrict__ x,
                                                        const float* __restrict__ gamma,
                                                        const float* __restrict__ beta,
                                                        const float2* __restrict__ stats,
                                                        unsigned short* __restrict__ xnt){
  __shared__ float tile[64][65];
  const int b = blockIdx.z, n0 = blockIdx.x*64, c0 = blockIdx.y*64;
  const float2 st = stats[b];
  const int t = threadIdx.x;
  const int col = t & 63, rb = t >> 6;
  #pragma unroll
  for (int i = 0; i < 16; ++i){
    int rr = i*4 + rb;
    float xv = x[((size_t)b*256 + c0 + rr)*4096 + n0 + col];
    tile[rr][col] = (xv - st.x) * st.y * gamma[c0+rr] + beta[c0+rr];
  }
  __syncthreads();
  #pragma unroll
  for (int i = 0; i < 16; ++i){
    int nr = i*4 + rb;
    xnt[((size_t)b*4096 + n0 + nr)*256 + c0 + col] = f2bf(tile[col][nr]);
  }
}

// ---------------- NT GEMM: C[m][n] = sum_k A[m][k]*B[n][k], K=256 ----------------
__global__ __launch_bounds__(256) void gemm_nt_k(const unsigned short* __restrict__ A,
                                                 const unsigned short* __restrict__ B,
                                                 int lda, int ldb, long sA, long sB,
                                                 const float* __restrict__ bias_m,
                                                 const float* __restrict__ bias_n,
                                                 const float* __restrict__ resid, long sR,
                                                 float* __restrict__ outF,
                                                 unsigned short* __restrict__ outB,
                                                 int ldc, long sC){
  __shared__ unsigned short As[64][40];
  __shared__ unsigned short Bs[64][40];
  const int b  = blockIdx.z;
  const int m0 = blockIdx.x * 64, n0 = blockIdx.y * 64;
  const unsigned short* Ab = A + (size_t)b * sA;
  const unsigned short* Bb = B + (size_t)b * sB;
  const int t = threadIdx.x;
  const int lane = t & 63, w = t >> 6;
  const int g = lane >> 4, r = lane & 15;
  const int wm = (w >> 1) * 32, wn = (w & 1) * 32;
  const int lrow = t >> 2, lcol = (t & 3) * 8;
  f32x4 acc00 = {0,0,0,0}, acc01 = {0,0,0,0}, acc10 = {0,0,0,0}, acc11 = {0,0,0,0};
  for (int ks = 0; ks < 8; ++ks){
    short8 av = *(const short8*)(Ab + (size_t)(m0 + lrow) * lda + ks*32 + lcol);
    short8 bv = *(const short8*)(Bb + (size_t)(n0 + lrow) * ldb + ks*32 + lcol);
    __syncthreads();
    *(short8*)&As[lrow][lcol] = av;
    *(short8*)&Bs[lrow][lcol] = bv;
    __syncthreads();
    short8 af0 = *(const short8*)&As[wm + r][g*8];
    short8 af1 = *(const short8*)&As[wm + 16 + r][g*8];
    short8 bf0 = *(const short8*)&Bs[wn + r][g*8];
    short8 bf1 = *(const short8*)&Bs[wn + 16 + r][g*8];
    acc00 = __builtin_amdgcn_mfma_f32_16x16x32_bf16(af0, bf0, acc00, 0, 0, 0);
    acc01 = __builtin_amdgcn_mfma_f32_16x16x32_bf16(af0, bf1, acc01, 0, 0, 0);
    acc10 = __builtin_amdgcn_mfma_f32_16x16x32_bf16(af1, bf0, acc10, 0, 0, 0);
    acc11 = __builtin_amdgcn_mfma_f32_16x16x32_bf16(af1, bf1, acc11, 0, 0, 0);
  }
  f32x4 accs[2][2] = {{acc00, acc01},{acc10, acc11}};
  #pragma unroll
  for (int mi = 0; mi < 2; ++mi)
    #pragma unroll
    for (int ni = 0; ni < 2; ++ni)
      #pragma unroll
      for (int j = 0; j < 4; ++j){
        int gm = m0 + wm + mi*16 + g*4 + j;
        int gn = n0 + wn + ni*16 + r;
        float vv = accs[mi][ni][j];
        if (bias_m) vv += bias_m[gm];
        if (bias_n) vv += bias_n[gn];
        if (resid)  vv += resid[(size_t)b*sR + (size_t)gm*ldc + gn];
        size_t off = (size_t)b*sC + (size_t)gm*ldc + gn;
        if (outB) outB[off] = f2bf(vv); else outF[off] = vv;
      }
}

// ---------------- flash attention, 8 waves: groups of 4 waves split the k-range ----------------
// q,k in qk[b][n][512] (q=c<256, k=c>=256), v in vbuf[b][c][n]. Output ho[b][n][c] bf16.
__global__ __launch_bounds__(512, 2) void attn_k(const unsigned short* __restrict__ qk,
                                                 const unsigned short* __restrict__ vbuf,
                                                 unsigned short* __restrict__ ho){
  // dense strides + XOR swizzle (byte ^= (row&7)<<4) on all row-indexed reads/writes
  __shared__ __align__(16) unsigned short Ks[2][64][256];   // 64 KB  [half][k_row][c]
  __shared__ __align__(16) unsigned short Vs[2][256][64];   // 64 KB  [half][c][k_row]
  __shared__ __align__(16) unsigned short Ps[2][64][64];    // 16 KB  [half][q_row][k_row]
  const int b = blockIdx.y, q0 = blockIdx.x * 64;
  const int t = threadIdx.x;
  const int w = t >> 6;            // 0..7
  const int h = w >> 2;            // k-range half
  const int wq = w & 3;            // q sub-block (16 rows)
  const int lane = t & 63, g = lane >> 4, r = lane & 15;
  const unsigned short* qkb = qk + (size_t)b * 4096 * 512;
  const unsigned short* vb  = vbuf + (size_t)b * 256 * 4096;

  // Q fragments (rows q0 + wq*16 + r), pre-scaled by C^-0.5*log2e at weight conversion
  short8 qf[8];
  {
    const unsigned short* qrow = qkb + (size_t)(q0 + wq*16 + r) * 512;
    #pragma unroll
    for (int kk = 0; kk < 8; ++kk) qf[kk] = *(const short8*)(qrow + kk*32 + g*8);
  }
  f32x4 oacc[16];
  #pragma unroll
  for (int i = 0; i < 16; ++i) oacc[i] = (f32x4){0.f,0.f,0.f,0.f};
  float mref[4] = {-1e30f,-1e30f,-1e30f,-1e30f};
  float lrun[4] = {0.f,0.f,0.f,0.f};

  char* ksb = (char*)Ks[h];
  char* vsb = (char*)Vs[h];
  char* psb = (char*)Ps[h];

  for (int kt = 0; kt < 32; ++kt){
    const int k0 = h*2048 + kt*64;
    __syncthreads();   // prior tile's LDS reads done before overwrite
    // stage K tile: 64 rows x 512B, linear LDS dest, swizzled global source
    #pragma unroll
    for (int i = 0; i < 8; ++i){
      int ii = wq*8 + i;
      int row = 2*ii + (lane >> 5);
      int c = lane & 31;
      const unsigned short* src = qkb + (size_t)(k0 + row)*512 + 256 + ((c ^ (row & 7)) * 8);
      gload16(src, ksb + ii*1024);
    }
    // stage V tile: 256 rows x 128B
    #pragma unroll
    for (int i = 0; i < 8; ++i){
      int ii = wq*8 + i;
      int row = 8*ii + (lane >> 3);
      int c = lane & 7;
      const unsigned short* src = vb + (size_t)row*4096 + k0 + ((c ^ (row & 7)) * 8);
      gload16(src, vsb + ii*1024);
    }
    __syncthreads();   // compiler drains vmcnt before barrier

    // S = Q K^T : 4 k-blocks of 16
    f32x4 sf[4];
    #pragma unroll
    for (int kb = 0; kb < 4; ++kb) sf[kb] = (f32x4){0.f,0.f,0.f,0.f};
    #pragma unroll
    for (int kk = 0; kk < 8; ++kk){
      #pragma unroll
      for (int kb = 0; kb < 4; ++kb){
        int row = kb*16 + r;
        int off = (row*512 + kk*64 + g*16) ^ ((row & 7) << 4);
        short8 kf = *(const short8*)(ksb + off);
        sf[kb] = __builtin_amdgcn_mfma_f32_16x16x32_bf16(qf[kk], kf, sf[kb], 0, 0, 0);
      }
    }

    // online softmax, defer-max (THR=8 in log2 domain): no shuffles in steady state
    float mloc[4]; bool need = false;
    #pragma unroll
    for (int j = 0; j < 4; ++j){
      float a = fmaxf(fmaxf(sf[0][j], sf[1][j]), fmaxf(sf[2][j], sf[3][j]));
      mloc[j] = a; need |= (a > mref[j] + 8.0f);
    }
    if (__any(need)){
      #pragma unroll
      for (int j = 0; j < 4; ++j){
        float mt = mloc[j];
        mt = fmaxf(mt, __shfl_xor(mt, 1));
        mt = fmaxf(mt, __shfl_xor(mt, 2));
        mt = fmaxf(mt, __shfl_xor(mt, 4));
        mt = fmaxf(mt, __shfl_xor(mt, 8));
        float mnew = fmaxf(mref[j], mt);
        float al = exp2f(mref[j] - mnew);
        lrun[j] *= al;
        #pragma unroll
        for (int cb = 0; cb < 16; ++cb) oacc[cb][j] *= al;
        mref[j] = mnew;
      }
    }
    #pragma unroll
    for (int j = 0; j < 4; ++j){
      int prow = wq*16 + g*4 + j;
      int rowoff = prow*128, sw = (prow & 7) << 4;
      float p0 = exp2f(sf[0][j] - mref[j]);
      float p1 = exp2f(sf[1][j] - mref[j]);
      float p2 = exp2f(sf[2][j] - mref[j]);
      float p3 = exp2f(sf[3][j] - mref[j]);
      lrun[j] += (p0 + p1) + (p2 + p3);   // lane-partial; reduced once at end
      *(unsigned short*)(psb + ((rowoff + (r     )*2) ^ sw)) = f2bf(p0);
      *(unsigned short*)(psb + ((rowoff + (r + 16)*2) ^ sw)) = f2bf(p1);
      *(unsigned short*)(psb + ((rowoff + (r + 32)*2) ^ sw)) = f2bf(p2);
      *(unsigned short*)(psb + ((rowoff + (r + 48)*2) ^ sw)) = f2bf(p3);
    }

    // O += P V   (within-wave LDS round trip; compiler inserts lgkm waits)
    #pragma unroll
    for (int hh = 0; hh < 2; ++hh){
      int arow = wq*16 + r;
      int aoff = (arow*128 + hh*64 + g*16) ^ ((arow & 7) << 4);
      short8 pa = *(const short8*)(psb + aoff);
      #pragma unroll
      for (int cb = 0; cb < 16; ++cb){
        int vrow = cb*16 + r;
        int voff = (vrow*128 + hh*64 + g*16) ^ ((vrow & 7) << 4);
        short8 vv = *(const short8*)(vsb + voff);
        oacc[cb] = __builtin_amdgcn_mfma_f32_16x16x32_bf16(pa, vv, oacc[cb], 0, 0, 0);
      }
    }
  }

  // finalize lane-distributed l (reduce across the 16 r-lanes)
  #pragma unroll
  for (int j = 0; j < 4; ++j){
    float l = lrun[j];
    l += __shfl_xor(l, 1); l += __shfl_xor(l, 2);
    l += __shfl_xor(l, 4); l += __shfl_xor(l, 8);
    lrun[j] = l;
  }
  // merge the two k-halves through LDS (overlay on Ks/Ps)
  __syncthreads();
  float*  Ob  = (float*)Ks;     // [64][256] f32 = 64 KB
  float2* Mlb = (float2*)Ps;    // [64]
  if (h == 1){
    #pragma unroll
    for (int cb = 0; cb < 16; ++cb)
      #pragma unroll
      for (int j = 0; j < 4; ++j)
        Ob[(wq*16 + g*4 + j)*256 + cb*16 + r] = oacc[cb][j];
    if (r == 0){
      #pragma unroll
      for (int j = 0; j < 4; ++j) Mlb[wq*16 + g*4 + j] = make_float2(mref[j], lrun[j]);
    }
  }
  __syncthreads();
  if (h == 0){
    float a0[4], a1[4], inv[4];
    #pragma unroll
    for (int j = 0; j < 4; ++j){
      float2 ml1 = Mlb[wq*16 + g*4 + j];
      float M  = fmaxf(mref[j], ml1.x);
      float e0 = exp2f(mref[j] - M), e1 = exp2f(ml1.x - M);
      float L  = lrun[j]*e0 + ml1.y*e1;
      a0[j] = e0; a1[j] = e1; inv[j] = 1.0f / L;
    }
    #pragma unroll
    for (int cb = 0; cb < 16; ++cb)
      #pragma unroll
      for (int j = 0; j < 4; ++j){
        float v1 = Ob[(wq*16 + g*4 + j)*256 + cb*16 + r];
        float val = (oacc[cb][j]*a0[j] + v1*a1[j]) * inv[j];
        ho[((size_t)(b*4096 + q0 + wq*16 + g*4 + j))*256 + cb*16 + r] = f2bf(val);
      }
  }
}

// ---------------- launch ----------------
extern "C" void kernel_launch(void* const* d_in, const int* in_sizes, int n_in,
                              void* d_out, int out_size, void* d_ws, size_t ws_size,
                              hipStream_t stream){
  const float* x      = (const float*)d_in[0];
  const float* gamma  = (const float*)d_in[1];
  const float* beta   = (const float*)d_in[2];
  const float* qkv_w  = (const float*)d_in[3];
  const float* qkv_b  = (const float*)d_in[4];
  const float* proj_w = (const float*)d_in[5];
  const float* proj_b = (const float*)d_in[6];
  float* out = (float*)d_out;
  char* ws = (char*)d_ws;

  float2* partial        = (float2*)(ws + 0);        // 2048 B
  float2* stats          = (float2*)(ws + 2048);     // 32 B
  float*  bias_qk        = (float*)(ws + 4096);      // 2048 B
  unsigned short* Wqk    = (unsigned short*)(ws + 8192);      // 512x256 bf16
  unsigned short* Wv     = (unsigned short*)(ws + 270336);    // 256x256
  unsigned short* Wp     = (unsigned short*)(ws + 401408);    // 256x256
  unsigned short* xnt    = (unsigned short*)(ws + 532480);    // 4x4096x256 bf16 (8.4 MB)
  unsigned short* qkbuf  = (unsigned short*)(ws + 8921088);   // 4x4096x512 bf16 (16.8 MB)
  unsigned short* vbuf   = (unsigned short*)(ws + 25698304);  // 4x256x4096 bf16 (8.4 MB)
  unsigned short* ho     = xnt;  // xnt dead after QKV gemms -> reuse for attention output

  reduce_partial_k<<<dim3(64,4), 256, 0, stream>>>(x, partial);
  reduce_final_k<<<1, 256, 0, stream>>>(partial, stats);
  convert_w_k<<<1024, 256, 0, stream>>>(qkv_w, qkv_b, proj_w, Wqk, Wv, Wp, bias_qk);
  norm_transpose_k<<<dim3(64,4,4), 256, 0, stream>>>(x, gamma, beta, stats, xnt);
  // qk[b][n][o] = xn_t[b][n][:] . Wqk[o][:]   (M=4096, N=512)
  gemm_nt_k<<<dim3(64,8,4), 256, 0, stream>>>(xnt, Wqk, 256, 256, 4096L*256, 0,
      nullptr, bias_qk, nullptr, 0, nullptr, qkbuf, 512, 4096L*512);
  // v[b][o][n] = Wv[o][:] . xn_t[b][n][:]     (M=256, N=4096)
  gemm_nt_k<<<dim3(4,64,4), 256, 0, stream>>>(Wv, xnt, 256, 256, 0, 4096L*256,
      qkv_b + 512, nullptr, nullptr, 0, nullptr, vbuf, 4096, 256L*4096);
  attn_k<<<dim3(64,4), 512, 0, stream>>>(qkbuf, vbuf, ho);
  // out[b][o][n] = Wp[o][:] . ho[b][n][:] + proj_b[o] + x[b][o][n]
  gemm_nt_k<<<dim3(4,64,4), 256, 0, stream>>>(Wp, ho, 256, 256, 0, 4096L*256,
      proj_b, nullptr, x, 1048576L, out, nullptr, 4096, 1048576L);
}